// Round 12
// baseline (288.164 us; speedup 1.0000x reference)
//
#include <hip/hip_runtime.h>
#include <hip/hip_bf16.h>

typedef unsigned short u16;
typedef unsigned int u32;
typedef __bf16 bf16x8 __attribute__((ext_vector_type(8)));
typedef float f32x4 __attribute__((ext_vector_type(4)));

#define MFMA16(a, b, c) __builtin_amdgcn_mfma_f32_16x16x32_bf16(a, b, c, 0, 0, 0)

static __device__ __forceinline__ u16 f2b(float f) {
  u32 u = __float_as_uint(f);
  return (u16)((u + 0x7FFFu + ((u >> 16) & 1u)) >> 16);
}
static __device__ __forceinline__ float blo(u32 u) { return __uint_as_float(u << 16); }
static __device__ __forceinline__ float bhi(u32 u) { return __uint_as_float(u & 0xffff0000u); }
static __device__ __forceinline__ u32 packtrunc(float a, float b) {
  return (__float_as_uint(a) >> 16) | (__float_as_uint(b) & 0xffff0000u);
}
static __device__ __forceinline__ bf16x8 mk8(u32 a, u32 b, u32 c, u32 d) {
  union { u32 u[4]; bf16x8 v; } t; t.u[0] = a; t.u[1] = b; t.u[2] = c; t.u[3] = d; return t.v;
}

// async 16B/lane global->LDS DMA; dst = uniform base + lane*16
static __device__ __forceinline__ void async_copy16(void* lds, const void* gp) {
  __builtin_amdgcn_global_load_lds(
      (const __attribute__((address_space(1))) unsigned int*)gp,
      (__attribute__((address_space(3))) unsigned int*)lds, 16, 0, 0);
}

// ---------------- fused prep: edge-degree count + x cast + weight transpose/cast ----------------
__global__ void prep_kernel(const int* __restrict__ dst, int* __restrict__ degi, int E,
                            const float* __restrict__ x, u16* __restrict__ xb, int n4,
                            const float* __restrict__ W1, const float* __restrict__ Ws,
                            const float* __restrict__ W2, const float* __restrict__ Wq,
                            const float* __restrict__ Wk, const float* __restrict__ Wv,
                            u16* __restrict__ wout) {
  int t = blockIdx.x * 256 + threadIdx.x;
  if (t < E) { atomicAdd(&degi[dst[t]], 1); return; }
  int t2 = t - E;
  if (t2 < n4) {
    float4 v = *(const float4*)&x[t2 * 4];
    ushort4 o;
    o.x = f2b(v.x); o.y = f2b(v.y); o.z = f2b(v.z); o.w = f2b(v.w);
    *(ushort4*)&xb[t2 * 4] = o;
    return;
  }
  int u = t2 - n4;
  if (u >= 131072) return;
  const float* src; int K, base, loc;
  if (u < 65536) {
    if (u < 32768) { src = W1; base = 0; } else { src = Ws; base = 32768; }
    loc = u - base; K = 256;
  } else {
    int seg = (u - 65536) >> 14;
    src = (seg == 0) ? W2 : (seg == 1) ? Wq : (seg == 2) ? Wk : Wv;
    base = 65536 + seg * 16384; loc = u & 16383; K = 128;
  }
  int k = loc >> 7, c = loc & 127;           // src [K,128]
  wout[base + c * K + k] = f2b(src[loc]);    // out [128,K]
}

// dis + CSR starts (wave-scan, one atomic per wave)
__global__ void dis_start_kernel(const int* __restrict__ degi, float* __restrict__ d,
                                 int* __restrict__ startb, int* __restrict__ counter, int N) {
  int i = blockIdx.x * 256 + threadIdx.x;
  int lane = threadIdx.x & 63;
  int dg = (i < N) ? degi[i] : 0;
  if (i < N) d[i] = rsqrtf((float)dg + 1.0f);  // +1 = self loop
  int x = dg;
#pragma unroll
  for (int ofs = 1; ofs < 64; ofs <<= 1) {
    int y = __shfl_up(x, ofs, 64);
    if (lane >= ofs) x += y;
  }
  int waveTotal = __shfl(x, 63, 64);
  int base = 0;
  if (lane == 63) base = atomicAdd(counter, waveTotal);
  base = __shfl(base, 63, 64);
  if (i < N) startb[i] = base + x - dg;  // exclusive
}

// ---------------- merged: CSR fill (edge blocks) + bgemm_dual (gemm blocks) ----------------
__global__ __launch_bounds__(256) void mid_kernel(
    const int* __restrict__ src, const int* __restrict__ dstp, const int* __restrict__ startb,
    int* __restrict__ cursor, int* __restrict__ adj, int E, int Gg,
    const u16* __restrict__ A, const u16* __restrict__ Wa, const u16* __restrict__ Wb,
    const float* __restrict__ bsb, u16* __restrict__ outa, float* __restrict__ outb, int M)
{
  if ((int)blockIdx.x >= Gg) {
    int e = (blockIdx.x - Gg) * 256 + threadIdx.x;
    if (e < E) {
      int d = dstp[e];
      int p = atomicAdd(&cursor[d], 1);
      adj[startb[d] + p] = src[e];
    }
    return;
  }
  int wv = threadIdx.x >> 6;
  int lane = threadIdx.x & 63;
  int col = lane & 15, quad = lane >> 4;
  int row0 = (blockIdx.x * 2 + (wv >> 1)) * 16;
  if (row0 >= M) return;
  int cb = (wv & 1) * 64;
  int ar = row0 + col; if (ar > M - 1) ar = M - 1;
  const u16* ap = A + (size_t)ar * 256 + quad * 8;
  f32x4 Oa[4], Ob[4];
#pragma unroll
  for (int i = 0; i < 4; i++) {
    Oa[i][0] = 0.f; Oa[i][1] = 0.f; Oa[i][2] = 0.f; Oa[i][3] = 0.f;
    Ob[i] = Oa[i];
  }
#pragma unroll
  for (int k0 = 0; k0 < 256; k0 += 32) {
    bf16x8 aA = *(const bf16x8*)(ap + k0);
#pragma unroll
    for (int nb = 0; nb < 4; nb++) {
      size_t wofs = (size_t)(cb + nb * 16 + col) * 256 + k0 + quad * 8;
      Oa[nb] = MFMA16(aA, *(const bf16x8*)(Wa + wofs), Oa[nb]);
      Ob[nb] = MFMA16(aA, *(const bf16x8*)(Wb + wofs), Ob[nb]);
    }
  }
#pragma unroll
  for (int nb = 0; nb < 4; nb++) {
    int ch = cb + nb * 16 + col;
    float bv = bsb[ch];
#pragma unroll
    for (int r = 0; r < 4; r++) {
      int row = row0 + quad * 4 + r;
      if (row >= M) continue;
      outa[(size_t)row * 128 + ch] = f2b(Oa[nb][r]);
      outb[(size_t)row * 128 + ch] = Ob[nb][r] + bv;
    }
  }
}

// ---------------- one wave gathers one row ----------------
static __device__ __forceinline__ void gather_one_row(
    const u16* __restrict__ h, const float* __restrict__ dis,
    const int* __restrict__ adj, const int* __restrict__ startb, const int* __restrict__ degi,
    const float* __restrict__ bias, const float* __restrict__ g, const float* __restrict__ beta,
    u16* AoRow, float* curOut, int row, int N, int do_silu)
{
  int lane = threadIdx.x & 63;
  int c2 = lane * 2;
  float o0 = 0.f, o1 = 0.f;
  if (row < N) {
    int st = startb[row], dg = degi[row];
    float v0 = 0.f, v1 = 0.f;
    for (int base = 0; base < dg; base += 64) {
      int nb = min(64, dg - base);
      int myadj = 0; float mydis = 0.f;
      if (lane < nb) { myadj = adj[st + base + lane]; mydis = dis[myadj]; }
      int jj = 0;
      for (; jj + 8 <= nb; jj += 8) {
        int s0 = __shfl(myadj, jj),     s1 = __shfl(myadj, jj + 1);
        int s2 = __shfl(myadj, jj + 2), s3 = __shfl(myadj, jj + 3);
        int s4 = __shfl(myadj, jj + 4), s5 = __shfl(myadj, jj + 5);
        int s6 = __shfl(myadj, jj + 6), s7 = __shfl(myadj, jj + 7);
        float w0 = __shfl(mydis, jj),     w1 = __shfl(mydis, jj + 1);
        float w2 = __shfl(mydis, jj + 2), w3 = __shfl(mydis, jj + 3);
        float w4 = __shfl(mydis, jj + 4), w5 = __shfl(mydis, jj + 5);
        float w6 = __shfl(mydis, jj + 6), w7 = __shfl(mydis, jj + 7);
        u32 a0 = *(const u32*)&h[(size_t)s0 * 128 + c2];
        u32 a1 = *(const u32*)&h[(size_t)s1 * 128 + c2];
        u32 a2 = *(const u32*)&h[(size_t)s2 * 128 + c2];
        u32 a3 = *(const u32*)&h[(size_t)s3 * 128 + c2];
        u32 a4 = *(const u32*)&h[(size_t)s4 * 128 + c2];
        u32 a5 = *(const u32*)&h[(size_t)s5 * 128 + c2];
        u32 a6 = *(const u32*)&h[(size_t)s6 * 128 + c2];
        u32 a7 = *(const u32*)&h[(size_t)s7 * 128 + c2];
        v0 += w0 * blo(a0); v1 += w0 * bhi(a0);
        v0 += w1 * blo(a1); v1 += w1 * bhi(a1);
        v0 += w2 * blo(a2); v1 += w2 * bhi(a2);
        v0 += w3 * blo(a3); v1 += w3 * bhi(a3);
        v0 += w4 * blo(a4); v1 += w4 * bhi(a4);
        v0 += w5 * blo(a5); v1 += w5 * bhi(a5);
        v0 += w6 * blo(a6); v1 += w6 * bhi(a6);
        v0 += w7 * blo(a7); v1 += w7 * bhi(a7);
      }
      for (; jj < nb; jj++) {
        int s = __shfl(myadj, jj);
        float wv = __shfl(mydis, jj);
        u32 a = *(const u32*)&h[(size_t)s * 128 + c2];
        v0 += wv * blo(a); v1 += wv * bhi(a);
      }
    }
    float dd = dis[row];
    u32 aself = *(const u32*)&h[(size_t)row * 128 + c2];
    v0 = (v0 + dd * blo(aself)) * dd + bias[c2];
    v1 = (v1 + dd * bhi(aself)) * dd + bias[c2 + 1];
    float s = v0 + v1;
#pragma unroll
    for (int d = 32; d > 0; d >>= 1) s += __shfl_xor(s, d, 64);
    float mu = s * (1.0f / 128.0f);
    float d0 = v0 - mu, d1 = v1 - mu;
    float q = d0 * d0 + d1 * d1;
#pragma unroll
    for (int d = 32; d > 0; d >>= 1) q += __shfl_xor(q, d, 64);
    float rstd = rsqrtf(q * (1.0f / 128.0f) + 1e-5f);
    o0 = d0 * rstd * g[c2]     + beta[c2];
    o1 = d1 * rstd * g[c2 + 1] + beta[c2 + 1];
    if (do_silu) {
      o0 = o0 / (1.f + __expf(-o0));
      o1 = o1 / (1.f + __expf(-o1));
    }
    if (curOut) *(float2*)&curOut[(size_t)row * 128 + c2] = make_float2(o0, o1);
  }
  *(u32*)&AoRow[c2] = (u32)f2b(o0) | ((u32)f2b(o1) << 16);
}

// ---------------- fused (16 waves): out1 = silu(LN1(gather(h1)+b1)); h2 = out1@W2 ----------------
__global__ __launch_bounds__(1024) void gather_gemm1(
    const u16* __restrict__ h, const float* __restrict__ dis,
    const int* __restrict__ adj, const int* __restrict__ startb, const int* __restrict__ degi,
    const float* __restrict__ b1, const float* __restrict__ g1, const float* __restrict__ be1,
    const u16* __restrict__ W2t, u16* __restrict__ h2, int N)
{
  __shared__ __align__(16) u16 Ao[16 * 136];
  int wv = threadIdx.x >> 6;
  int row0 = blockIdx.x * 16;
  gather_one_row(h, dis, adj, startb, degi, b1, g1, be1, &Ao[wv * 136], nullptr,
                 row0 + wv, N, 1);
  __syncthreads();
  if (wv >= 8) return;
  int lane = threadIdx.x & 63;
  int col = lane & 15, quad = lane >> 4;
  f32x4 acc; acc[0] = 0.f; acc[1] = 0.f; acc[2] = 0.f; acc[3] = 0.f;
#pragma unroll
  for (int ks = 0; ks < 4; ks++) {
    bf16x8 aA = *(const bf16x8*)&Ao[col * 136 + ks * 32 + quad * 8];
    const u16* bp = W2t + (size_t)(wv * 16 + col) * 128 + ks * 32 + quad * 8;
    acc = MFMA16(aA, *(const bf16x8*)bp, acc);
  }
  int ch = wv * 16 + col;
#pragma unroll
  for (int r = 0; r < 4; r++) {
    int row = row0 + quad * 4 + r;
    if (row < N) h2[(size_t)row * 128 + ch] = f2b(acc[r]);
  }
}

// ---------------- fused (16 waves): out2 = LN2(gather(h2)+b2) -> cur; Q,K,V GEMMs ----------------
__global__ __launch_bounds__(1024) void gather_gemm_qkv(
    const u16* __restrict__ h2, const float* __restrict__ dis,
    const int* __restrict__ adj, const int* __restrict__ startb, const int* __restrict__ degi,
    const float* __restrict__ b2, const float* __restrict__ g2, const float* __restrict__ be2,
    const u16* __restrict__ Wqt, const u16* __restrict__ Wkt, const u16* __restrict__ Wvt,
    const float* __restrict__ bq, const float* __restrict__ bk, const float* __restrict__ bvb,
    float* __restrict__ cur, u16* __restrict__ q_out, u16* __restrict__ k_out,
    u16* __restrict__ v_out, int N, int NP, float qscale)
{
  __shared__ __align__(16) u16 Ao[16 * 136];
  int wv = threadIdx.x >> 6;
  int row0 = blockIdx.x * 16;
  gather_one_row(h2, dis, adj, startb, degi, b2, g2, be2, &Ao[wv * 136], cur,
                 row0 + wv, N, 0);
  __syncthreads();
  int lane = threadIdx.x & 63;
  int col = lane & 15, quad = lane >> 4;
  {
    const u16* Wt = (wv < 8) ? Wqt : Wkt;
    const float* bb = (wv < 8) ? bq : bk;
    int cb = (wv & 7) * 16;
    f32x4 acc; acc[0] = 0.f; acc[1] = 0.f; acc[2] = 0.f; acc[3] = 0.f;
#pragma unroll
    for (int ks = 0; ks < 4; ks++) {
      bf16x8 aA = *(const bf16x8*)&Ao[col * 136 + ks * 32 + quad * 8];
      const u16* bp = Wt + (size_t)(cb + col) * 128 + ks * 32 + quad * 8;
      acc = MFMA16(aA, *(const bf16x8*)bp, acc);
    }
    int ch = cb + col;
    float bv = bb[ch];
    if (wv < 8) {
#pragma unroll
      for (int r = 0; r < 4; r++) {
        int row = row0 + quad * 4 + r;
        if (row < N) q_out[(size_t)row * 128 + ch] = f2b((acc[r] + bv) * qscale);
      }
    } else {
#pragma unroll
      for (int r = 0; r < 4; r++) {
        int row = row0 + quad * 4 + r;
        if (row < N) k_out[(size_t)row * 128 + ch] = f2b(acc[r] + bv);
      }
    }
  }
  if (wv < 8) {
    int cb = wv * 16;
    f32x4 acc; acc[0] = 0.f; acc[1] = 0.f; acc[2] = 0.f; acc[3] = 0.f;
#pragma unroll
    for (int ks = 0; ks < 4; ks++) {
      bf16x8 aA = *(const bf16x8*)&Ao[col * 136 + ks * 32 + quad * 8];
      const u16* bp = Wvt + (size_t)(cb + col) * 128 + ks * 32 + quad * 8;
      acc = MFMA16(aA, *(const bf16x8*)bp, acc);
    }
    int ch = cb + col;
    float bv = bvb[ch];
#pragma unroll
    for (int r = 0; r < 4; r++) {
      int row = row0 + quad * 4 + r;
      if (row < N) v_out[(size_t)ch * NP + row] = f2b(acc[r] + bv);
    }
  }
}

// ---------------- flash attention partial: S^T + bpermute, TRIPLE-buffered DMA ----------------
// AITER-style pipeline: loop-top "s_waitcnt vmcnt(4); s_barrier" leaves the NEXT tile's
// 4 DMAs in flight across the barrier (only current tile's must have landed); tile kt+2
// staged after the barrier. Each tile's DMA gets ~2 compute phases to complete instead
// of a forced vmcnt(0) drain every tile (R7-R11 structure).
__global__ __launch_bounds__(256, 3) void flash_part(
    const u16* __restrict__ qb, const u16* __restrict__ kb, const u16* __restrict__ vt,
    u16* __restrict__ Opart, float* __restrict__ lpart,
    int N, int NP, int NPB, int CHUNK)
{
  __shared__ __align__(16) u16 Kl[3][32 * 128];  // [key][128ch], chunk ^= key&7
  __shared__ __align__(16) u16 Vl[3][128 * 32];  // [ch][32key], chunk ^= (ch>>1)&3
  int tid = threadIdx.x;
  int w = tid >> 6, lane = tid & 63;
  int col = lane & 15, quad = lane >> 4;
  int h8 = col & 7;
  int ks = blockIdx.y;
  int kstart = ks * CHUNK;
  int qbase = blockIdx.x * 128 + w * 32;

  bf16x8 aQ[2][4];
#pragma unroll
  for (int rg = 0; rg < 2; rg++) {
    int qr = qbase + rg * 16 + col; if (qr > N - 1) qr = N - 1;
    const u16* qp = qb + (size_t)qr * 128 + quad * 8;
    aQ[rg][0] = *(const bf16x8*)(qp);
    aQ[rg][1] = *(const bf16x8*)(qp + 32);
    aQ[rg][2] = *(const bf16x8*)(qp + 64);
    aQ[rg][3] = *(const bf16x8*)(qp + 96);
  }

  f32x4 O[2][8];
#pragma unroll
  for (int rg = 0; rg < 2; rg++)
#pragma unroll
    for (int i = 0; i < 8; i++) { O[rg][i][0] = 0.f; O[rg][i][1] = 0.f; O[rg][i][2] = 0.f; O[rg][i][3] = 0.f; }
  float lr0 = 0.f, lr1 = 0.f;

  int l16 = lane >> 4, c16 = lane & 15;  // K staging: 4 rows x 16 chunks / instr
  int vch = lane >> 2, vc4 = lane & 3;   // V staging: 16 ch x 4 chunks / instr

  int idxA = (((quad & 1) * 2 + 0) * 16 + col) * 4;
  int idxB = (((quad & 1) * 2 + 1) * 16 + col) * 4;
  bool hiKg = (quad >= 2);

  auto stage = [&](int buf, int k0) {   // 4 DMA instrs per wave
#pragma unroll
    for (int i = 0; i < 2; i++) {
      int rl = w * 8 + i * 4 + l16;
      int cg = c16 ^ (rl & 7);
      async_copy16(&Kl[buf][(w * 8 + i * 4) * 128], kb + (size_t)(k0 + rl) * 128 + cg * 8);
    }
#pragma unroll
    for (int i = 0; i < 2; i++) {
      int ch = w * 32 + i * 16 + vch;
      int cg = vc4 ^ ((ch >> 1) & 3);
      async_copy16(&Vl[buf][(w * 32 + i * 16) * 32], vt + (size_t)ch * NP + k0 + cg * 8);
    }
  };

  int KT = (min(CHUNK, NP - kstart)) >> 5;
  stage(0, kstart);
  if (KT > 1) stage(1, kstart + 32);

  int buf = 0, sbuf = 2;
  for (int kt = 0; kt < KT; kt++) {
    int k0 = kstart + (kt << 5);
    // tile kt's DMAs done; tile kt+1's (if any) stay in flight across the barrier
    if (kt + 1 < KT) asm volatile("s_waitcnt vmcnt(4)\n\ts_barrier" ::: "memory");
    else             asm volatile("s_waitcnt vmcnt(0)\n\ts_barrier" ::: "memory");
    if (kt + 2 < KT) stage(sbuf, k0 + 64);  // lands during the next ~2 compute phases

    const u16* Kb = &Kl[buf][0];
    const u16* Vb = &Vl[buf][0];

    f32x4 sT[2][2];
#pragma unroll
    for (int kg = 0; kg < 2; kg++) {
      const u16* kr = Kb + (kg * 16 + col) * 128;
      bf16x8 kf0 = *(const bf16x8*)(kr + (((0 + quad) ^ h8) << 3));
      bf16x8 kf1 = *(const bf16x8*)(kr + (((4 + quad) ^ h8) << 3));
      bf16x8 kf2 = *(const bf16x8*)(kr + (((8 + quad) ^ h8) << 3));
      bf16x8 kf3 = *(const bf16x8*)(kr + (((12 + quad) ^ h8) << 3));
      f32x4 s0; s0[0] = 0.f; s0[1] = 0.f; s0[2] = 0.f; s0[3] = 0.f;
      f32x4 s1 = s0;
      s0 = MFMA16(kf0, aQ[0][0], s0); s1 = MFMA16(kf0, aQ[1][0], s1);
      s0 = MFMA16(kf1, aQ[0][1], s0); s1 = MFMA16(kf1, aQ[1][1], s1);
      s0 = MFMA16(kf2, aQ[0][2], s0); s1 = MFMA16(kf2, aQ[1][2], s1);
      s0 = MFMA16(kf3, aQ[0][3], s0); s1 = MFMA16(kf3, aQ[1][3], s1);
      sT[kg][0] = s0; sT[kg][1] = s1;
    }
    if (k0 + 32 > N) {
#pragma unroll
      for (int kg = 0; kg < 2; kg++) {
        int kbase = k0 + kg * 16 + quad * 4;
#pragma unroll
        for (int r = 0; r < 4; r++) {
          if (kbase + r >= N) { sT[kg][0][r] = -1e30f; sT[kg][1][r] = -1e30f; }
        }
      }
    }
    u32 plo[2][2], phi[2][2];
#pragma unroll
    for (int kg = 0; kg < 2; kg++) {
      float p00 = __expf(sT[kg][0][0]), p01 = __expf(sT[kg][0][1]);
      float p02 = __expf(sT[kg][0][2]), p03 = __expf(sT[kg][0][3]);
      float p10 = __expf(sT[kg][1][0]), p11 = __expf(sT[kg][1][1]);
      float p12 = __expf(sT[kg][1][2]), p13 = __expf(sT[kg][1][3]);
      lr0 += p00 + p01 + p02 + p03;
      lr1 += p10 + p11 + p12 + p13;
      plo[kg][0] = packtrunc(p00, p01); phi[kg][0] = packtrunc(p02, p03);
      plo[kg][1] = packtrunc(p10, p11); phi[kg][1] = packtrunc(p12, p13);
    }
    bf16x8 bP[2];
#pragma unroll
    for (int rg = 0; rg < 2; rg++) {
      int loA0 = __builtin_amdgcn_ds_bpermute(idxA, (int)plo[0][rg]);
      int loA1 = __builtin_amdgcn_ds_bpermute(idxA, (int)plo[1][rg]);
      int hiA0 = __builtin_amdgcn_ds_bpermute(idxA, (int)phi[0][rg]);
      int hiA1 = __builtin_amdgcn_ds_bpermute(idxA, (int)phi[1][rg]);
      int loB0 = __builtin_amdgcn_ds_bpermute(idxB, (int)plo[0][rg]);
      int loB1 = __builtin_amdgcn_ds_bpermute(idxB, (int)plo[1][rg]);
      int hiB0 = __builtin_amdgcn_ds_bpermute(idxB, (int)phi[0][rg]);
      int hiB1 = __builtin_amdgcn_ds_bpermute(idxB, (int)phi[1][rg]);
      u32 j01 = hiKg ? (u32)loA1 : (u32)loA0;
      u32 j23 = hiKg ? (u32)hiA1 : (u32)hiA0;
      u32 j45 = hiKg ? (u32)loB1 : (u32)loB0;
      u32 j67 = hiKg ? (u32)hiB1 : (u32)hiB0;
      bP[rg] = mk8(j01, j23, j45, j67);
    }
#pragma unroll
    for (int nb = 0; nb < 8; nb++) {
      int ch = nb * 16 + col;
      const u16* vr = Vb + ch * 32;
      bf16x8 vf = *(const bf16x8*)(vr + ((quad ^ ((ch >> 1) & 3)) << 3));
      O[0][nb] = MFMA16(vf, bP[0], O[0][nb]);
      O[1][nb] = MFMA16(vf, bP[1], O[1][nb]);
    }
    buf = (buf == 2) ? 0 : buf + 1;
    sbuf = (sbuf == 2) ? 0 : sbuf + 1;
  }

  lr0 += __shfl_xor(lr0, 16, 64); lr0 += __shfl_xor(lr0, 32, 64);
  lr1 += __shfl_xor(lr1, 16, 64); lr1 += __shfl_xor(lr1, 32, 64);
  if (lane < 16) {
    lpart[(size_t)ks * NPB + qbase + lane] = lr0;
    lpart[(size_t)ks * NPB + qbase + 16 + lane] = lr1;
  }
#pragma unroll
  for (int rg = 0; rg < 2; rg++) {
    int row = qbase + rg * 16 + col;
    u16* dstrow = Opart + ((size_t)ks * NPB + row) * 128 + quad * 4;
#pragma unroll
    for (int nb = 0; nb < 8; nb++) {
      u32 w01 = (u32)f2b(O[rg][nb][0]) | ((u32)f2b(O[rg][nb][1]) << 16);
      u32 w23 = (u32)f2b(O[rg][nb][2]) | ((u32)f2b(O[rg][nb][3]) << 16);
      *(uint2*)(dstrow + nb * 16) = make_uint2(w01, w23);
    }
  }
}

// ---------------- combine K-split partials + out2 + identity + SiLU ----------------
__global__ __launch_bounds__(256) void attn_combine(
    const u16* __restrict__ Opart, const float* __restrict__ lpart,
    const float* __restrict__ out2, const float* __restrict__ ident, float* __restrict__ out,
    int N, int NPB, int S)
{
  int row = blockIdx.x * 4 + (threadIdx.x >> 6);
  int c2 = (threadIdx.x & 63) * 2;
  if (row >= N) return;
  float num0 = 0.f, num1 = 0.f, den = 0.f;
  for (int u = 0; u < S; u++) {
    u32 b = *(const u32*)&Opart[((size_t)u * NPB + row) * 128 + c2];
    num0 += blo(b); num1 += bhi(b);
    den += lpart[(size_t)u * NPB + row];
  }
  size_t idx = (size_t)row * 128 + c2;
  float rinv = 1.0f / den;
  float2 o2 = *(const float2*)&out2[idx];
  float2 id = *(const float2*)&ident[idx];
  float v0 = num0 * rinv + o2.x + id.x;
  float v1 = num1 * rinv + o2.y + id.y;
  v0 = v0 / (1.f + __expf(-v0));
  v1 = v1 / (1.f + __expf(-v1));
  *(float2*)&out[idx] = make_float2(v0, v1);
}

extern "C" void kernel_launch(void* const* d_in, const int* in_sizes, int n_in,
                              void* d_out, int out_size, void* d_ws, size_t ws_size,
                              hipStream_t stream) {
  const float* x   = (const float*)d_in[0];
  const int*   ei  = (const int*)d_in[1];
  const float* W1  = (const float*)d_in[2];
  const float* b1  = (const float*)d_in[3];
  const float* W2  = (const float*)d_in[4];
  const float* b2  = (const float*)d_in[5];
  const float* g1  = (const float*)d_in[6];
  const float* be1 = (const float*)d_in[7];
  const float* g2  = (const float*)d_in[8];
  const float* be2 = (const float*)d_in[9];
  const float* Wq  = (const float*)d_in[10];
  const float* bq  = (const float*)d_in[11];
  const float* Wk  = (const float*)d_in[12];
  const float* bk  = (const float*)d_in[13];
  const float* Wv  = (const float*)d_in[14];
  const float* bv  = (const float*)d_in[15];
  const float* Wsw = (const float*)d_in[16];
  const float* bs  = (const float*)d_in[17];

  const int CIN = 256, C = 128;
  int N = in_sizes[0] / CIN;
  int E = in_sizes[1] / 2;
  int NP = (N + 63) & ~63;     // key-dim padding
  int NPB = (N + 127) & ~127;  // q-row-dim padding for partials
  const int* src = ei;
  const int* dstp = ei + E;

  const int S = 8;
  int tiles = NP / 64;
  int CHUNK = ((tiles + S - 1) / S) * 64;  // keys per split, mult of 64 (and 32)

  char* w = (char*)d_ws;
  size_t off = 0;
  auto alloc = [&](size_t bytes) -> void* {
    void* p = w + off;
    off = (off + bytes + 255) & ~(size_t)255;
    return p;
  };
  // degi/cursor/counter contiguous -> one memset
  int*   degi   = (int*)alloc((size_t)N * 4);
  int*   cursor = (int*)alloc((size_t)N * 4);
  int*   counter= (int*)alloc(256);
  size_t zlen   = off;
  float* disb   = (float*)alloc((size_t)N * 4);
  int*   startb = (int*)alloc((size_t)N * 4);
  int*   adj    = (int*)alloc((size_t)E * 4);
  u16*   h      = (u16*)alloc((size_t)N * C * 2);   // bf16 h1
  u16*   h2     = (u16*)alloc((size_t)N * C * 2);   // bf16 h2
  float* ident  = (float*)alloc((size_t)N * C * 4);
  float* cur    = (float*)alloc((size_t)N * C * 4); // f32 out2
  u16*   xb     = (u16*)alloc((size_t)N * CIN * 2);
  u16*   wt     = (u16*)alloc((size_t)131072 * 2);
  u16*   qbb    = (u16*)alloc((size_t)N * C * 2);
  u16*   kbb    = (u16*)alloc((size_t)NP * C * 2);
  u16*   vt     = (u16*)alloc((size_t)C * NP * 2);
  u16*   Opart  = (u16*)alloc((size_t)S * NPB * C * 2);
  float* lpart  = (float*)alloc((size_t)S * NPB * 4);

  u16* wt1 = wt;            // [128,256]
  u16* wts = wt + 32768;    // [128,256]
  u16* wt2 = wt + 65536;    // [128,128]
  u16* wtq = wt + 81920;
  u16* wtk = wt + 98304;
  u16* wtv = wt + 114688;

  hipMemsetAsync(degi, 0, zlen, stream);

  int n4 = N * CIN / 4;
  int ptot = E + n4 + 131072;
  prep_kernel<<<(ptot + 255) / 256, 256, 0, stream>>>(dstp, degi, E, x, xb, n4,
                                                      W1, Wsw, W2, Wq, Wk, Wv, wt);
  int gN = (N + 255) / 256;
  dis_start_kernel<<<gN, 256, 0, stream>>>(degi, disb, startb, counter, N);

  // merged fill + dual GEMM
  int rowtiles = (N + 15) / 16;
  int Gg = (rowtiles + 1) / 2;
  int gE = (E + 255) / 256;
  mid_kernel<<<Gg + gE, 256, 0, stream>>>(src, dstp, startb, cursor, adj, E, Gg,
                                          xb, wt1, wts, bs, h, ident, N);

  int gRows = (N + 15) / 16;
  gather_gemm1<<<gRows, 1024, 0, stream>>>(h, disb, adj, startb, degi, b1, g1, be1,
                                           wt2, h2, N);

  const float qscale = 0.08838834764831845f;  // 1/sqrt(128)
  gather_gemm_qkv<<<gRows, 1024, 0, stream>>>(h2, disb, adj, startb, degi, b2, g2, be2,
                                              wtq, wtk, wtv, bq, bk, bv,
                                              cur, qbb, kbb, vt, N, NP, qscale);

  dim3 fg(NPB / 128, S);
  flash_part<<<fg, 256, 0, stream>>>(qbb, kbb, vt, Opart, lpart, N, NP, NPB, CHUNK);
  attn_combine<<<(N + 3) / 4, 256, 0, stream>>>(Opart, lpart, cur, ident,
                                                (float*)d_out, N, NPB, S);
}

// Round 13
// 268.977 us; speedup vs baseline: 1.0713x; 1.0713x over previous
//
#include <hip/hip_runtime.h>
#include <hip/hip_bf16.h>

typedef unsigned short u16;
typedef unsigned int u32;
typedef __bf16 bf16x8 __attribute__((ext_vector_type(8)));
typedef float f32x4 __attribute__((ext_vector_type(4)));

#define MFMA16(a, b, c) __builtin_amdgcn_mfma_f32_16x16x32_bf16(a, b, c, 0, 0, 0)

static __device__ __forceinline__ u16 f2b(float f) {
  u32 u = __float_as_uint(f);
  return (u16)((u + 0x7FFFu + ((u >> 16) & 1u)) >> 16);
}
static __device__ __forceinline__ float blo(u32 u) { return __uint_as_float(u << 16); }
static __device__ __forceinline__ float bhi(u32 u) { return __uint_as_float(u & 0xffff0000u); }
static __device__ __forceinline__ u32 packtrunc(float a, float b) {
  return (__float_as_uint(a) >> 16) | (__float_as_uint(b) & 0xffff0000u);
}
static __device__ __forceinline__ bf16x8 mk8(u32 a, u32 b, u32 c, u32 d) {
  union { u32 u[4]; bf16x8 v; } t; t.u[0] = a; t.u[1] = b; t.u[2] = c; t.u[3] = d; return t.v;
}

// async 16B/lane global->LDS DMA; dst = uniform base + lane*16
static __device__ __forceinline__ void async_copy16(void* lds, const void* gp) {
  __builtin_amdgcn_global_load_lds(
      (const __attribute__((address_space(1))) unsigned int*)gp,
      (__attribute__((address_space(3))) unsigned int*)lds, 16, 0, 0);
}

// ---------------- fused prep: edge-degree count + x cast + weight transpose/cast ----------------
__global__ void prep_kernel(const int* __restrict__ dst, int* __restrict__ degi, int E,
                            const float* __restrict__ x, u16* __restrict__ xb, int n4,
                            const float* __restrict__ W1, const float* __restrict__ Ws,
                            const float* __restrict__ W2, const float* __restrict__ Wq,
                            const float* __restrict__ Wk, const float* __restrict__ Wv,
                            u16* __restrict__ wout) {
  int t = blockIdx.x * 256 + threadIdx.x;
  if (t < E) { atomicAdd(&degi[dst[t]], 1); return; }
  int t2 = t - E;
  if (t2 < n4) {
    float4 v = *(const float4*)&x[t2 * 4];
    ushort4 o;
    o.x = f2b(v.x); o.y = f2b(v.y); o.z = f2b(v.z); o.w = f2b(v.w);
    *(ushort4*)&xb[t2 * 4] = o;
    return;
  }
  int u = t2 - n4;
  if (u >= 131072) return;
  const float* src; int K, base, loc;
  if (u < 65536) {
    if (u < 32768) { src = W1; base = 0; } else { src = Ws; base = 32768; }
    loc = u - base; K = 256;
  } else {
    int seg = (u - 65536) >> 14;
    src = (seg == 0) ? W2 : (seg == 1) ? Wq : (seg == 2) ? Wk : Wv;
    base = 65536 + seg * 16384; loc = u & 16383; K = 128;
  }
  int k = loc >> 7, c = loc & 127;           // src [K,128]
  wout[base + c * K + k] = f2b(src[loc]);    // out [128,K]
}

// dis + CSR starts (wave-scan, one atomic per wave)
__global__ void dis_start_kernel(const int* __restrict__ degi, float* __restrict__ d,
                                 int* __restrict__ startb, int* __restrict__ counter, int N) {
  int i = blockIdx.x * 256 + threadIdx.x;
  int lane = threadIdx.x & 63;
  int dg = (i < N) ? degi[i] : 0;
  if (i < N) d[i] = rsqrtf((float)dg + 1.0f);  // +1 = self loop
  int x = dg;
#pragma unroll
  for (int ofs = 1; ofs < 64; ofs <<= 1) {
    int y = __shfl_up(x, ofs, 64);
    if (lane >= ofs) x += y;
  }
  int waveTotal = __shfl(x, 63, 64);
  int base = 0;
  if (lane == 63) base = atomicAdd(counter, waveTotal);
  base = __shfl(base, 63, 64);
  if (i < N) startb[i] = base + x - dg;  // exclusive
}

// ---------------- merged: CSR fill (edge blocks) + bgemm_dual (gemm blocks) ----------------
__global__ __launch_bounds__(256) void mid_kernel(
    const int* __restrict__ src, const int* __restrict__ dstp, const int* __restrict__ startb,
    int* __restrict__ cursor, int* __restrict__ adj, int E, int Gg,
    const u16* __restrict__ A, const u16* __restrict__ Wa, const u16* __restrict__ Wb,
    const float* __restrict__ bsb, u16* __restrict__ outa, float* __restrict__ outb, int M)
{
  if ((int)blockIdx.x >= Gg) {
    int e = (blockIdx.x - Gg) * 256 + threadIdx.x;
    if (e < E) {
      int d = dstp[e];
      int p = atomicAdd(&cursor[d], 1);
      adj[startb[d] + p] = src[e];
    }
    return;
  }
  int wv = threadIdx.x >> 6;
  int lane = threadIdx.x & 63;
  int col = lane & 15, quad = lane >> 4;
  int row0 = (blockIdx.x * 2 + (wv >> 1)) * 16;
  if (row0 >= M) return;
  int cb = (wv & 1) * 64;
  int ar = row0 + col; if (ar > M - 1) ar = M - 1;
  const u16* ap = A + (size_t)ar * 256 + quad * 8;
  f32x4 Oa[4], Ob[4];
#pragma unroll
  for (int i = 0; i < 4; i++) {
    Oa[i][0] = 0.f; Oa[i][1] = 0.f; Oa[i][2] = 0.f; Oa[i][3] = 0.f;
    Ob[i] = Oa[i];
  }
#pragma unroll
  for (int k0 = 0; k0 < 256; k0 += 32) {
    bf16x8 aA = *(const bf16x8*)(ap + k0);
#pragma unroll
    for (int nb = 0; nb < 4; nb++) {
      size_t wofs = (size_t)(cb + nb * 16 + col) * 256 + k0 + quad * 8;
      Oa[nb] = MFMA16(aA, *(const bf16x8*)(Wa + wofs), Oa[nb]);
      Ob[nb] = MFMA16(aA, *(const bf16x8*)(Wb + wofs), Ob[nb]);
    }
  }
#pragma unroll
  for (int nb = 0; nb < 4; nb++) {
    int ch = cb + nb * 16 + col;
    float bv = bsb[ch];
#pragma unroll
    for (int r = 0; r < 4; r++) {
      int row = row0 + quad * 4 + r;
      if (row >= M) continue;
      outa[(size_t)row * 128 + ch] = f2b(Oa[nb][r]);
      outb[(size_t)row * 128 + ch] = Ob[nb][r] + bv;
    }
  }
}

// ---------------- one wave gathers one row ----------------
static __device__ __forceinline__ void gather_one_row(
    const u16* __restrict__ h, const float* __restrict__ dis,
    const int* __restrict__ adj, const int* __restrict__ startb, const int* __restrict__ degi,
    const float* __restrict__ bias, const float* __restrict__ g, const float* __restrict__ beta,
    u16* AoRow, float* curOut, int row, int N, int do_silu)
{
  int lane = threadIdx.x & 63;
  int c2 = lane * 2;
  float o0 = 0.f, o1 = 0.f;
  if (row < N) {
    int st = startb[row], dg = degi[row];
    float v0 = 0.f, v1 = 0.f;
    for (int base = 0; base < dg; base += 64) {
      int nb = min(64, dg - base);
      int myadj = 0; float mydis = 0.f;
      if (lane < nb) { myadj = adj[st + base + lane]; mydis = dis[myadj]; }
      int jj = 0;
      for (; jj + 8 <= nb; jj += 8) {
        int s0 = __shfl(myadj, jj),     s1 = __shfl(myadj, jj + 1);
        int s2 = __shfl(myadj, jj + 2), s3 = __shfl(myadj, jj + 3);
        int s4 = __shfl(myadj, jj + 4), s5 = __shfl(myadj, jj + 5);
        int s6 = __shfl(myadj, jj + 6), s7 = __shfl(myadj, jj + 7);
        float w0 = __shfl(mydis, jj),     w1 = __shfl(mydis, jj + 1);
        float w2 = __shfl(mydis, jj + 2), w3 = __shfl(mydis, jj + 3);
        float w4 = __shfl(mydis, jj + 4), w5 = __shfl(mydis, jj + 5);
        float w6 = __shfl(mydis, jj + 6), w7 = __shfl(mydis, jj + 7);
        u32 a0 = *(const u32*)&h[(size_t)s0 * 128 + c2];
        u32 a1 = *(const u32*)&h[(size_t)s1 * 128 + c2];
        u32 a2 = *(const u32*)&h[(size_t)s2 * 128 + c2];
        u32 a3 = *(const u32*)&h[(size_t)s3 * 128 + c2];
        u32 a4 = *(const u32*)&h[(size_t)s4 * 128 + c2];
        u32 a5 = *(const u32*)&h[(size_t)s5 * 128 + c2];
        u32 a6 = *(const u32*)&h[(size_t)s6 * 128 + c2];
        u32 a7 = *(const u32*)&h[(size_t)s7 * 128 + c2];
        v0 += w0 * blo(a0); v1 += w0 * bhi(a0);
        v0 += w1 * blo(a1); v1 += w1 * bhi(a1);
        v0 += w2 * blo(a2); v1 += w2 * bhi(a2);
        v0 += w3 * blo(a3); v1 += w3 * bhi(a3);
        v0 += w4 * blo(a4); v1 += w4 * bhi(a4);
        v0 += w5 * blo(a5); v1 += w5 * bhi(a5);
        v0 += w6 * blo(a6); v1 += w6 * bhi(a6);
        v0 += w7 * blo(a7); v1 += w7 * bhi(a7);
      }
      for (; jj < nb; jj++) {
        int s = __shfl(myadj, jj);
        float wv = __shfl(mydis, jj);
        u32 a = *(const u32*)&h[(size_t)s * 128 + c2];
        v0 += wv * blo(a); v1 += wv * bhi(a);
      }
    }
    float dd = dis[row];
    u32 aself = *(const u32*)&h[(size_t)row * 128 + c2];
    v0 = (v0 + dd * blo(aself)) * dd + bias[c2];
    v1 = (v1 + dd * bhi(aself)) * dd + bias[c2 + 1];
    float s = v0 + v1;
#pragma unroll
    for (int d = 32; d > 0; d >>= 1) s += __shfl_xor(s, d, 64);
    float mu = s * (1.0f / 128.0f);
    float d0 = v0 - mu, d1 = v1 - mu;
    float q = d0 * d0 + d1 * d1;
#pragma unroll
    for (int d = 32; d > 0; d >>= 1) q += __shfl_xor(q, d, 64);
    float rstd = rsqrtf(q * (1.0f / 128.0f) + 1e-5f);
    o0 = d0 * rstd * g[c2]     + beta[c2];
    o1 = d1 * rstd * g[c2 + 1] + beta[c2 + 1];
    if (do_silu) {
      o0 = o0 / (1.f + __expf(-o0));
      o1 = o1 / (1.f + __expf(-o1));
    }
    if (curOut) *(float2*)&curOut[(size_t)row * 128 + c2] = make_float2(o0, o1);
  }
  *(u32*)&AoRow[c2] = (u32)f2b(o0) | ((u32)f2b(o1) << 16);
}

// ---------------- fused (16 waves): out1 = silu(LN1(gather(h1)+b1)); h2 = out1@W2 ----------------
__global__ __launch_bounds__(1024) void gather_gemm1(
    const u16* __restrict__ h, const float* __restrict__ dis,
    const int* __restrict__ adj, const int* __restrict__ startb, const int* __restrict__ degi,
    const float* __restrict__ b1, const float* __restrict__ g1, const float* __restrict__ be1,
    const u16* __restrict__ W2t, u16* __restrict__ h2, int N)
{
  __shared__ __align__(16) u16 Ao[16 * 136];
  int wv = threadIdx.x >> 6;
  int row0 = blockIdx.x * 16;
  gather_one_row(h, dis, adj, startb, degi, b1, g1, be1, &Ao[wv * 136], nullptr,
                 row0 + wv, N, 1);
  __syncthreads();
  if (wv >= 8) return;
  int lane = threadIdx.x & 63;
  int col = lane & 15, quad = lane >> 4;
  f32x4 acc; acc[0] = 0.f; acc[1] = 0.f; acc[2] = 0.f; acc[3] = 0.f;
#pragma unroll
  for (int ks = 0; ks < 4; ks++) {
    bf16x8 aA = *(const bf16x8*)&Ao[col * 136 + ks * 32 + quad * 8];
    const u16* bp = W2t + (size_t)(wv * 16 + col) * 128 + ks * 32 + quad * 8;
    acc = MFMA16(aA, *(const bf16x8*)bp, acc);
  }
  int ch = wv * 16 + col;
#pragma unroll
  for (int r = 0; r < 4; r++) {
    int row = row0 + quad * 4 + r;
    if (row < N) h2[(size_t)row * 128 + ch] = f2b(acc[r]);
  }
}

// ---------------- fused (16 waves): out2 = LN2(gather(h2)+b2) -> cur; Q,K,V GEMMs ----------------
// V is stored with keys PI-PERMUTED within each 32-row block (slot = q*8 + kg*4 + r for
// key kg*16+q*4+r) so flash's PV B-frag needs NO cross-lane relayout (see flash_part).
__global__ __launch_bounds__(1024) void gather_gemm_qkv(
    const u16* __restrict__ h2, const float* __restrict__ dis,
    const int* __restrict__ adj, const int* __restrict__ startb, const int* __restrict__ degi,
    const float* __restrict__ b2, const float* __restrict__ g2, const float* __restrict__ be2,
    const u16* __restrict__ Wqt, const u16* __restrict__ Wkt, const u16* __restrict__ Wvt,
    const float* __restrict__ bq, const float* __restrict__ bk, const float* __restrict__ bvb,
    float* __restrict__ cur, u16* __restrict__ q_out, u16* __restrict__ k_out,
    u16* __restrict__ v_out, int N, int NP, float qscale)
{
  __shared__ __align__(16) u16 Ao[16 * 136];
  int wv = threadIdx.x >> 6;
  int row0 = blockIdx.x * 16;
  gather_one_row(h2, dis, adj, startb, degi, b2, g2, be2, &Ao[wv * 136], cur,
                 row0 + wv, N, 0);
  __syncthreads();
  int lane = threadIdx.x & 63;
  int col = lane & 15, quad = lane >> 4;
  {
    const u16* Wt = (wv < 8) ? Wqt : Wkt;
    const float* bb = (wv < 8) ? bq : bk;
    int cb = (wv & 7) * 16;
    f32x4 acc; acc[0] = 0.f; acc[1] = 0.f; acc[2] = 0.f; acc[3] = 0.f;
#pragma unroll
    for (int ks = 0; ks < 4; ks++) {
      bf16x8 aA = *(const bf16x8*)&Ao[col * 136 + ks * 32 + quad * 8];
      const u16* bp = Wt + (size_t)(cb + col) * 128 + ks * 32 + quad * 8;
      acc = MFMA16(aA, *(const bf16x8*)bp, acc);
    }
    int ch = cb + col;
    float bv = bb[ch];
    if (wv < 8) {
#pragma unroll
      for (int r = 0; r < 4; r++) {
        int row = row0 + quad * 4 + r;
        if (row < N) q_out[(size_t)row * 128 + ch] = f2b((acc[r] + bv) * qscale);
      }
    } else {
#pragma unroll
      for (int r = 0; r < 4; r++) {
        int row = row0 + quad * 4 + r;
        if (row < N) k_out[(size_t)row * 128 + ch] = f2b(acc[r] + bv);
      }
    }
  }
  if (wv < 8) {
    int cb = wv * 16;
    f32x4 acc; acc[0] = 0.f; acc[1] = 0.f; acc[2] = 0.f; acc[3] = 0.f;
#pragma unroll
    for (int ks = 0; ks < 4; ks++) {
      bf16x8 aA = *(const bf16x8*)&Ao[col * 136 + ks * 32 + quad * 8];
      const u16* bp = Wvt + (size_t)(cb + col) * 128 + ks * 32 + quad * 8;
      acc = MFMA16(aA, *(const bf16x8*)bp, acc);
    }
    int ch = cb + col;
    float bv = bvb[ch];
#pragma unroll
    for (int r = 0; r < 4; r++) {
      int row = row0 + quad * 4 + r;
      if (row < N) {
        int rb = row & 31;
        int slot = (((rb >> 2) & 3) << 3) + ((rb >> 4) << 2) + (rb & 3);  // pi^-1
        v_out[(size_t)ch * NP + (row & ~31) + slot] = f2b(acc[r] + bv);
      }
    }
  }
}

// ---------------- flash attention partial: S^T + pi-permuted V (zero P relayout) ----------------
// S^T = K@Q^T; lane (quad q, qrow=col) holds keys {4q..4q+3, 16+4q..16+4q+3} — exactly
// slots {8q..8q+7} under pi. V stored key-permuted by pi, so the PV B-frag is a direct
// register pack {P_kg0 r0..r3, P_kg1 r0..r3}: NO bpermute, NO LDS round-trip (R12 ledger:
// the 16 bpermutes were ~33% of the per-CU LDS budget, the flash limiter).
__global__ __launch_bounds__(256, 3) void flash_part(
    const u16* __restrict__ qb, const u16* __restrict__ kb, const u16* __restrict__ vt,
    u16* __restrict__ Opart, float* __restrict__ lpart,
    int N, int NP, int NPB, int CHUNK)
{
  __shared__ __align__(16) u16 Kl[3][32 * 128];  // [key][128ch], chunk ^= key&7
  __shared__ __align__(16) u16 Vl[3][128 * 32];  // [ch][32 pi-slots], chunk ^= (ch>>1)&3
  int tid = threadIdx.x;
  int w = tid >> 6, lane = tid & 63;
  int col = lane & 15, quad = lane >> 4;
  int h8 = col & 7;
  int ks = blockIdx.y;
  int kstart = ks * CHUNK;
  int qbase = blockIdx.x * 128 + w * 32;

  bf16x8 aQ[2][4];
#pragma unroll
  for (int rg = 0; rg < 2; rg++) {
    int qr = qbase + rg * 16 + col; if (qr > N - 1) qr = N - 1;
    const u16* qp = qb + (size_t)qr * 128 + quad * 8;
    aQ[rg][0] = *(const bf16x8*)(qp);
    aQ[rg][1] = *(const bf16x8*)(qp + 32);
    aQ[rg][2] = *(const bf16x8*)(qp + 64);
    aQ[rg][3] = *(const bf16x8*)(qp + 96);
  }

  f32x4 O[2][8];
#pragma unroll
  for (int rg = 0; rg < 2; rg++)
#pragma unroll
    for (int i = 0; i < 8; i++) { O[rg][i][0] = 0.f; O[rg][i][1] = 0.f; O[rg][i][2] = 0.f; O[rg][i][3] = 0.f; }
  float lr0 = 0.f, lr1 = 0.f;

  int l16 = lane >> 4, c16 = lane & 15;  // K staging: 4 rows x 16 chunks / instr
  int vch = lane >> 2, vc4 = lane & 3;   // V staging: 16 ch x 4 chunks / instr

  auto stage = [&](int buf, int k0) {   // 4 DMA instrs per wave
#pragma unroll
    for (int i = 0; i < 2; i++) {
      int rl = w * 8 + i * 4 + l16;
      int cg = c16 ^ (rl & 7);
      async_copy16(&Kl[buf][(w * 8 + i * 4) * 128], kb + (size_t)(k0 + rl) * 128 + cg * 8);
    }
#pragma unroll
    for (int i = 0; i < 2; i++) {
      int ch = w * 32 + i * 16 + vch;
      int cg = vc4 ^ ((ch >> 1) & 3);
      async_copy16(&Vl[buf][(w * 32 + i * 16) * 32], vt + (size_t)ch * NP + k0 + cg * 8);
    }
  };

  int KT = (min(CHUNK, NP - kstart)) >> 5;
  stage(0, kstart);
  if (KT > 1) stage(1, kstart + 32);

  int buf = 0, sbuf = 2;
  for (int kt = 0; kt < KT; kt++) {
    int k0 = kstart + (kt << 5);
    if (kt + 1 < KT) asm volatile("s_waitcnt vmcnt(4)\n\ts_barrier" ::: "memory");
    else             asm volatile("s_waitcnt vmcnt(0)\n\ts_barrier" ::: "memory");
    if (kt + 2 < KT) stage(sbuf, k0 + 64);

    const u16* Kb = &Kl[buf][0];
    const u16* Vb = &Vl[buf][0];

    f32x4 sT[2][2];
#pragma unroll
    for (int kg = 0; kg < 2; kg++) {
      const u16* kr = Kb + (kg * 16 + col) * 128;
      bf16x8 kf0 = *(const bf16x8*)(kr + (((0 + quad) ^ h8) << 3));
      bf16x8 kf1 = *(const bf16x8*)(kr + (((4 + quad) ^ h8) << 3));
      bf16x8 kf2 = *(const bf16x8*)(kr + (((8 + quad) ^ h8) << 3));
      bf16x8 kf3 = *(const bf16x8*)(kr + (((12 + quad) ^ h8) << 3));
      f32x4 s0; s0[0] = 0.f; s0[1] = 0.f; s0[2] = 0.f; s0[3] = 0.f;
      f32x4 s1 = s0;
      s0 = MFMA16(kf0, aQ[0][0], s0); s1 = MFMA16(kf0, aQ[1][0], s1);
      s0 = MFMA16(kf1, aQ[0][1], s0); s1 = MFMA16(kf1, aQ[1][1], s1);
      s0 = MFMA16(kf2, aQ[0][2], s0); s1 = MFMA16(kf2, aQ[1][2], s1);
      s0 = MFMA16(kf3, aQ[0][3], s0); s1 = MFMA16(kf3, aQ[1][3], s1);
      sT[kg][0] = s0; sT[kg][1] = s1;
    }
    if (k0 + 32 > N) {  // mask padded keys (key = k0 + kg*16 + quad*4 + r)
#pragma unroll
      for (int kg = 0; kg < 2; kg++) {
        int kbase = k0 + kg * 16 + quad * 4;
#pragma unroll
        for (int r = 0; r < 4; r++) {
          if (kbase + r >= N) { sT[kg][0][r] = -1e30f; sT[kg][1][r] = -1e30f; }
        }
      }
    }
    // exp + pack; B-frag is a direct pack thanks to pi-permuted V
    u32 plo[2][2], phi[2][2];
#pragma unroll
    for (int kg = 0; kg < 2; kg++) {
      float p00 = __expf(sT[kg][0][0]), p01 = __expf(sT[kg][0][1]);
      float p02 = __expf(sT[kg][0][2]), p03 = __expf(sT[kg][0][3]);
      float p10 = __expf(sT[kg][1][0]), p11 = __expf(sT[kg][1][1]);
      float p12 = __expf(sT[kg][1][2]), p13 = __expf(sT[kg][1][3]);
      lr0 += p00 + p01 + p02 + p03;
      lr1 += p10 + p11 + p12 + p13;
      plo[kg][0] = packtrunc(p00, p01); phi[kg][0] = packtrunc(p02, p03);
      plo[kg][1] = packtrunc(p10, p11); phi[kg][1] = packtrunc(p12, p13);
    }
    bf16x8 bP[2];
    bP[0] = mk8(plo[0][0], phi[0][0], plo[1][0], phi[1][0]);
    bP[1] = mk8(plo[0][1], phi[0][1], plo[1][1], phi[1][1]);
#pragma unroll
    for (int nb = 0; nb < 8; nb++) {
      int ch = nb * 16 + col;
      const u16* vr = Vb + ch * 32;
      bf16x8 vf = *(const bf16x8*)(vr + ((quad ^ ((ch >> 1) & 3)) << 3));
      O[0][nb] = MFMA16(vf, bP[0], O[0][nb]);
      O[1][nb] = MFMA16(vf, bP[1], O[1][nb]);
    }
    buf = (buf == 2) ? 0 : buf + 1;
    sbuf = (sbuf == 2) ? 0 : sbuf + 1;
  }

  lr0 += __shfl_xor(lr0, 16, 64); lr0 += __shfl_xor(lr0, 32, 64);
  lr1 += __shfl_xor(lr1, 16, 64); lr1 += __shfl_xor(lr1, 32, 64);
  if (lane < 16) {
    lpart[(size_t)ks * NPB + qbase + lane] = lr0;
    lpart[(size_t)ks * NPB + qbase + 16 + lane] = lr1;
  }
#pragma unroll
  for (int rg = 0; rg < 2; rg++) {
    int row = qbase + rg * 16 + col;
    u16* dstrow = Opart + ((size_t)ks * NPB + row) * 128 + quad * 4;
#pragma unroll
    for (int nb = 0; nb < 8; nb++) {
      u32 w01 = (u32)f2b(O[rg][nb][0]) | ((u32)f2b(O[rg][nb][1]) << 16);
      u32 w23 = (u32)f2b(O[rg][nb][2]) | ((u32)f2b(O[rg][nb][3]) << 16);
      *(uint2*)(dstrow + nb * 16) = make_uint2(w01, w23);
    }
  }
}

// ---------------- combine K-split partials + out2 + identity + SiLU ----------------
__global__ __launch_bounds__(256) void attn_combine(
    const u16* __restrict__ Opart, const float* __restrict__ lpart,
    const float* __restrict__ out2, const float* __restrict__ ident, float* __restrict__ out,
    int N, int NPB, int S)
{
  int row = blockIdx.x * 4 + (threadIdx.x >> 6);
  int c2 = (threadIdx.x & 63) * 2;
  if (row >= N) return;
  float num0 = 0.f, num1 = 0.f, den = 0.f;
  for (int u = 0; u < S; u++) {
    u32 b = *(const u32*)&Opart[((size_t)u * NPB + row) * 128 + c2];
    num0 += blo(b); num1 += bhi(b);
    den += lpart[(size_t)u * NPB + row];
  }
  size_t idx = (size_t)row * 128 + c2;
  float rinv = 1.0f / den;
  float2 o2 = *(const float2*)&out2[idx];
  float2 id = *(const float2*)&ident[idx];
  float v0 = num0 * rinv + o2.x + id.x;
  float v1 = num1 * rinv + o2.y + id.y;
  v0 = v0 / (1.f + __expf(-v0));
  v1 = v1 / (1.f + __expf(-v1));
  *(float2*)&out[idx] = make_float2(v0, v1);
}

extern "C" void kernel_launch(void* const* d_in, const int* in_sizes, int n_in,
                              void* d_out, int out_size, void* d_ws, size_t ws_size,
                              hipStream_t stream) {
  const float* x   = (const float*)d_in[0];
  const int*   ei  = (const int*)d_in[1];
  const float* W1  = (const float*)d_in[2];
  const float* b1  = (const float*)d_in[3];
  const float* W2  = (const float*)d_in[4];
  const float* b2  = (const float*)d_in[5];
  const float* g1  = (const float*)d_in[6];
  const float* be1 = (const float*)d_in[7];
  const float* g2  = (const float*)d_in[8];
  const float* be2 = (const float*)d_in[9];
  const float* Wq  = (const float*)d_in[10];
  const float* bq  = (const float*)d_in[11];
  const float* Wk  = (const float*)d_in[12];
  const float* bk  = (const float*)d_in[13];
  const float* Wv  = (const float*)d_in[14];
  const float* bv  = (const float*)d_in[15];
  const float* Wsw = (const float*)d_in[16];
  const float* bs  = (const float*)d_in[17];

  const int CIN = 256, C = 128;
  int N = in_sizes[0] / CIN;
  int E = in_sizes[1] / 2;
  int NP = (N + 63) & ~63;     // key-dim padding
  int NPB = (N + 127) & ~127;  // q-row-dim padding for partials
  const int* src = ei;
  const int* dstp = ei + E;

  const int S = 8;
  int tiles = NP / 64;
  int CHUNK = ((tiles + S - 1) / S) * 64;  // keys per split, mult of 64 (and 32)

  char* w = (char*)d_ws;
  size_t off = 0;
  auto alloc = [&](size_t bytes) -> void* {
    void* p = w + off;
    off = (off + bytes + 255) & ~(size_t)255;
    return p;
  };
  // degi/cursor/counter contiguous -> one memset
  int*   degi   = (int*)alloc((size_t)N * 4);
  int*   cursor = (int*)alloc((size_t)N * 4);
  int*   counter= (int*)alloc(256);
  size_t zlen   = off;
  float* disb   = (float*)alloc((size_t)N * 4);
  int*   startb = (int*)alloc((size_t)N * 4);
  int*   adj    = (int*)alloc((size_t)E * 4);
  u16*   h      = (u16*)alloc((size_t)N * C * 2);   // bf16 h1
  u16*   h2     = (u16*)alloc((size_t)N * C * 2);   // bf16 h2
  float* ident  = (float*)alloc((size_t)N * C * 4);
  float* cur    = (float*)alloc((size_t)N * C * 4); // f32 out2
  u16*   xb     = (u16*)alloc((size_t)N * CIN * 2);
  u16*   wt     = (u16*)alloc((size_t)131072 * 2);
  u16*   qbb    = (u16*)alloc((size_t)N * C * 2);
  u16*   kbb    = (u16*)alloc((size_t)NP * C * 2);
  u16*   vt     = (u16*)alloc((size_t)C * NP * 2);
  u16*   Opart  = (u16*)alloc((size_t)S * NPB * C * 2);
  float* lpart  = (float*)alloc((size_t)S * NPB * 4);

  u16* wt1 = wt;            // [128,256]
  u16* wts = wt + 32768;    // [128,256]
  u16* wt2 = wt + 65536;    // [128,128]
  u16* wtq = wt + 81920;
  u16* wtk = wt + 98304;
  u16* wtv = wt + 114688;

  hipMemsetAsync(degi, 0, zlen, stream);

  int n4 = N * CIN / 4;
  int ptot = E + n4 + 131072;
  prep_kernel<<<(ptot + 255) / 256, 256, 0, stream>>>(dstp, degi, E, x, xb, n4,
                                                      W1, Wsw, W2, Wq, Wk, Wv, wt);
  int gN = (N + 255) / 256;
  dis_start_kernel<<<gN, 256, 0, stream>>>(degi, disb, startb, counter, N);

  // merged fill + dual GEMM
  int rowtiles = (N + 15) / 16;
  int Gg = (rowtiles + 1) / 2;
  int gE = (E + 255) / 256;
  mid_kernel<<<Gg + gE, 256, 0, stream>>>(src, dstp, startb, cursor, adj, E, Gg,
                                          xb, wt1, wts, bs, h, ident, N);

  int gRows = (N + 15) / 16;
  gather_gemm1<<<gRows, 1024, 0, stream>>>(h, disb, adj, startb, degi, b1, g1, be1,
                                           wt2, h2, N);

  const float qscale = 0.08838834764831845f;  // 1/sqrt(128)
  gather_gemm_qkv<<<gRows, 1024, 0, stream>>>(h2, disb, adj, startb, degi, b2, g2, be2,
                                              wtq, wtk, wtv, bq, bk, bv,
                                              cur, qbb, kbb, vt, N, NP, qscale);

  dim3 fg(NPB / 128, S);
  flash_part<<<fg, 256, 0, stream>>>(qbb, kbb, vt, Opart, lpart, N, NP, NPB, CHUNK);
  attn_combine<<<(N + 3) / 4, 256, 0, stream>>>(Opart, lpart, cur, ident,
                                                (float*)d_out, N, NPB, S);
}